// Round 19
// baseline (30.980 us; speedup 1.0000x reference)
//
#include <hip/hip_runtime.h>
#include <math.h>

#define BLK   256
#define EPT   3
#define WIN   (BLK*EPT)   // 768 = chunk + 2*halo
#define CHUNK 512
#define HALO  128
#define NW    (BLK/64)    // 4 waves, exactly 1 per SIMD

typedef float v2f __attribute__((ext_vector_type(2)));

__device__ __forceinline__ float frcp(float x){ return __builtin_amdgcn_rcpf(x); }
__device__ __forceinline__ v2f mkv2(float x, float y){ v2f r; r.x=x; r.y=y; return r; }

// Tuples as 2x2 rows (v2f). Symmetric mats keep both rows (r1.x dups r0.y).
struct FT { v2f A0,A1,b,C0,C1,e,J0,J1; };   // filter scan tuple: 16 floats
struct BC { v2f b,C0,C1; };                  // filter prefix state (b,C only)
struct EJ { v2f e,J0,J1; };                  // backward info state (eta,J only)

template<typename T>
__device__ __forceinline__ T shflup(const T& v, int d){
  T r; const float* s=(const float*)&v; float* p=(float*)&r;
  constexpr int n = sizeof(T)/4;
  #pragma unroll
  for (int i=0;i<n;i++) p[i] = __shfl_up(s[i], (unsigned)d, 64);
  return r;
}
template<typename T>
__device__ __forceinline__ T shfldn(const T& v, int d){
  T r; const float* s=(const float*)&v; float* p=(float*)&r;
  constexpr int n = sizeof(T)/4;
  #pragma unroll
  for (int i=0;i<n;i++) p[i] = __shfl_down(s[i], (unsigned)d, 64);
  return r;
}
// comp-major LDS exchange
template<typename T>
__device__ __forceinline__ void lds_store(float (*arr)[NW], int col, const T& v){
  const float* s=(const float*)&v;
  constexpr int n = sizeof(T)/4;
  #pragma unroll
  for (int i=0;i<n;i++) arr[i][col] = s[i];
}
template<typename T>
__device__ __forceinline__ T lds_load(const float (*arr)[NW], int col){
  T r; float* p=(float*)&r;
  constexpr int n = sizeof(T)/4;
  #pragma unroll
  for (int i=0;i<n;i++) p[i] = arr[i][col];
  return r;
}

// ---------------------------------------------------------------------------
// Full filter combine (a = earlier/smaller k, b = later).
// ---------------------------------------------------------------------------
__device__ __forceinline__ FT comb_f(const FT& a, const FT& b){
  FT o;
  v2f T0 = a.C0.x*b.J0 + a.C0.y*b.J1; T0.x += 1.f;
  v2f T1 = a.C1.x*b.J0 + a.C1.y*b.J1; T1.y += 1.f;
  const float idet = frcp(T0.x*T1.y - T0.y*T1.x);
  const v2f M0 = idet * mkv2( T1.y, -T0.y);
  const v2f M1 = idet * mkv2(-T1.x,  T0.x);
  const v2f P0 = b.A0.x*M0 + b.A0.y*M1;
  const v2f P1 = b.A1.x*M0 + b.A1.y*M1;
  o.A0 = P0.x*a.A0 + P0.y*a.A1;
  o.A1 = P1.x*a.A0 + P1.y*a.A1;
  const v2f u = a.b + b.e.x*a.C0 + b.e.y*a.C1;
  o.b = mkv2(P0.x*u.x + P0.y*u.y + b.b.x,
             P1.x*u.x + P1.y*u.y + b.b.y);
  const v2f W0 = P0.x*a.C0 + P0.y*a.C1;
  const v2f W1 = P1.x*a.C0 + P1.y*a.C1;
  const float c00 = W0.x*b.A0.x + W0.y*b.A0.y + b.C0.x;
  const float c01 = W0.x*b.A1.x + W0.y*b.A1.y + b.C0.y;
  const float c11 = W1.x*b.A1.x + W1.y*b.A1.y + b.C1.y;
  o.C0 = mkv2(c00,c01); o.C1 = mkv2(c01,c11);
  const v2f v = b.e - (a.b.x*b.J0 + a.b.y*b.J1);
  const v2f Nv = v.x*M0 + v.y*M1;
  o.e = a.e + Nv.x*a.A0 + Nv.y*a.A1;
  const v2f X0 = M0.x*b.J0 + M1.x*b.J1;
  const v2f X1 = M0.y*b.J0 + M1.y*b.J1;
  const v2f Y0 = a.A0.x*X0 + a.A1.x*X1;
  const v2f Y1 = a.A0.y*X0 + a.A1.y*X1;
  const float j00 = Y0.x*a.A0.x + Y0.y*a.A1.x + a.J0.x;
  const float j01 = Y0.x*a.A0.y + Y0.y*a.A1.y + a.J0.y;
  const float j11 = Y1.x*a.A0.y + Y1.y*a.A1.y + a.J1.y;
  o.J0 = mkv2(j00,j01); o.J1 = mkv2(j01,j11);
  return o;
}

// Prefix step: a = accumulated prefix (only b,C live), b = next segment.
// a = {0,0,0} is an exact identity (C=0 -> M=I).
__device__ __forceinline__ BC comb_bc(const BC& a, const FT& b){
  BC o;
  v2f T0 = a.C0.x*b.J0 + a.C0.y*b.J1; T0.x += 1.f;
  v2f T1 = a.C1.x*b.J0 + a.C1.y*b.J1; T1.y += 1.f;
  const float idet = frcp(T0.x*T1.y - T0.y*T1.x);
  const v2f M0 = idet * mkv2( T1.y, -T0.y);
  const v2f M1 = idet * mkv2(-T1.x,  T0.x);
  const v2f P0 = b.A0.x*M0 + b.A0.y*M1;
  const v2f P1 = b.A1.x*M0 + b.A1.y*M1;
  const v2f u = a.b + b.e.x*a.C0 + b.e.y*a.C1;
  o.b = mkv2(P0.x*u.x + P0.y*u.y + b.b.x,
             P1.x*u.x + P1.y*u.y + b.b.y);
  const v2f W0 = P0.x*a.C0 + P0.y*a.C1;
  const v2f W1 = P1.x*a.C0 + P1.y*a.C1;
  const float c00 = W0.x*b.A0.x + W0.y*b.A0.y + b.C0.x;
  const float c01 = W0.x*b.A1.x + W0.y*b.A1.y + b.C0.y;
  const float c11 = W1.x*b.A1.x + W1.y*b.A1.y + b.C1.y;
  o.C0 = mkv2(c00,c01); o.C1 = mkv2(c01,c11);
  return o;
}

// Backward-info absorb: a = full segment (earlier k), b = suffix info (e,J)
// of everything after a. Output = (e,J) of [a, then b]. b = {0} is identity.
// (Exactly the e/J output lines of comb_f.)
__device__ __forceinline__ EJ comb_eJ(const FT& a, const EJ& b){
  EJ o;
  v2f T0 = a.C0.x*b.J0 + a.C0.y*b.J1; T0.x += 1.f;
  v2f T1 = a.C1.x*b.J0 + a.C1.y*b.J1; T1.y += 1.f;
  const float idet = frcp(T0.x*T1.y - T0.y*T1.x);
  const v2f M0 = idet * mkv2( T1.y, -T0.y);
  const v2f M1 = idet * mkv2(-T1.x,  T0.x);
  const v2f v = b.e - (a.b.x*b.J0 + a.b.y*b.J1);
  const v2f Nv = v.x*M0 + v.y*M1;
  o.e = a.e + Nv.x*a.A0 + Nv.y*a.A1;
  const v2f X0 = M0.x*b.J0 + M1.x*b.J1;
  const v2f X1 = M0.y*b.J0 + M1.y*b.J1;
  const v2f Y0 = a.A0.x*X0 + a.A1.x*X1;
  const v2f Y1 = a.A0.y*X0 + a.A1.y*X1;
  const float j00 = Y0.x*a.A0.x + Y0.y*a.A1.x + a.J0.x;
  const float j01 = Y0.x*a.A0.y + Y0.y*a.A1.y + a.J0.y;
  const float j11 = Y1.x*a.A0.y + Y1.y*a.A1.y + a.J1.y;
  o.J0 = mkv2(j00,j01); o.J1 = mkv2(j01,j11);
  return o;
}

// Two-filter merge: posterior from filtered N(mf,Pf) and future-obs info
// (e,J). m_s = (I+Pf J)^{-1}(mf + Pf e); P_s = (I+Pf J)^{-1} Pf. Only [0]
// components needed. (e,J)={0}: reduces to filtered moments exactly.
__device__ __forceinline__ void merge_out(const v2f mf, const v2f Pf0, const v2f Pf1,
    const EJ& s, float& oqm, float& oqv){
  const float U00 = Pf0.x*s.J0.x + Pf0.y*s.J0.y;
  const float U01 = Pf0.x*s.J0.y + Pf0.y*s.J1.y;
  const float U10 = Pf1.x*s.J0.x + Pf1.y*s.J0.y;
  const float U11 = Pf1.x*s.J0.y + Pf1.y*s.J1.y;
  const float T00 = 1.f + U00, T01 = U01, T10 = U10, T11 = 1.f + U11;
  const float idet = frcp(T00*T11 - T01*T10);
  const float w0 = mf.x + Pf0.x*s.e.x + Pf0.y*s.e.y;
  const float w1 = mf.y + Pf1.x*s.e.x + Pf1.y*s.e.y;
  oqm = idet*(T11*w0 - T01*w1);
  oqv = fmaxf(idet*(T11*Pf0.x - T01*Pf1.x), 1e-12f);
}

// f64 only here: Q = P_inf - A P_inf A^T cancels like (4/3)(lam dt)^3.
__device__ __forceinline__ void compute_fq(double dt, double lam, double s2,
    v2f& F0, v2f& F1, v2f& Q0, v2f& Q1){
  const double ld = lam*dt, e = exp(-ld), e2 = e*e;
  F0 = mkv2((float)(e*(1.0+ld)), (float)(e*dt));
  F1 = mkv2((float)(-lam*lam*dt*e), (float)(e*(1.0-ld)));
  const float q00 = (float)(s2*(1.0 - e2*((1.0+ld)*(1.0+ld)+ld*ld)));
  const float q01 = (float)(2.0*s2*lam*e2*ld*ld);
  const float q11 = (float)(lam*lam*s2*(1.0 - e2*(ld*ld+(1.0-ld)*(1.0-ld))));
  Q0 = mkv2(q00,q01); Q1 = mkv2(q01,q11);
}

__device__ __forceinline__ FT build_felem(bool prior,
    const v2f F0, const v2f F1, const v2f Q0, const v2f Q1,
    float n1, float n2, float sigma2, float lam2s2)
{
  FT e;
  const float R = frcp(n2);
  const float yy = n1*R;
  if (prior){
    e.A0 = mkv2(0.f,0.f); e.A1 = mkv2(0.f,0.f);
    const float K0 = sigma2*frcp(sigma2 + R);
    e.b = mkv2(K0*yy, 0.f);
    e.C0 = mkv2(sigma2 - K0*sigma2, 0.f); e.C1 = mkv2(0.f, lam2s2);
    e.e = mkv2(0.f,0.f); e.J0 = mkv2(0.f,0.f); e.J1 = mkv2(0.f,0.f);
  } else {
    const float iS = frcp(Q0.x + R);
    const float K0 = Q0.x*iS, K1 = Q0.y*iS;
    const float om = 1.f - K0;
    e.A0 = om*F0;
    e.A1 = F1 - K1*F0;
    e.b = mkv2(K0*yy, K1*yy);
    e.C0 = om*Q0;
    e.C1 = mkv2(e.C0.y, Q1.y - K1*Q0.y);
    e.e = (yy*iS)*F0;
    e.J0 = (iS*F0.x)*F0;
    e.J1 = mkv2(e.J0.y, iS*F0.y*F0.y);
  }
  return e;
}

// ---------------------------------------------------------------------------
// Fixed-lag windowed EP with TWO-FILTER smoothing: the forward prefix scan
// and backward suffix scan (same comb_f over the same lane composites) are
// INDEPENDENT and interleaved level-by-level -> the two dependent chains
// fill each other's stalls at 1 wave/SIMD. Suffix consumed as (e,J) only
// (comb_eJ chains over the shared shF wave aggregates); smoothed moments
// via a 20-op merge. One barrier/iter (double-buffered shF).
// ---------------------------------------------------------------------------
__global__ __launch_bounds__(BLK, 1) void fused_kernel(
    const float* __restrict__ times, const int* __restrict__ y,
    const float* __restrict__ ll, const float* __restrict__ lv,
    float* __restrict__ out, int N)
{
  __shared__ float shF[2][16][NW];   // wave full-FT aggregates, double-buffered

  const int t = threadIdx.x, b = blockIdx.x;
  const int lane = t & 63, w = t >> 6;
  const int cs = b * CHUNK;
  int ws = cs - HALO;
  if (ws < 0) ws = 0;
  if (ws > N - WIN) ws = N - WIN;
  const int g0 = ws + t * EPT;

  const double lamd    = sqrt(3.0)/exp((double)ll[0]);
  const double sigma2d = exp((double)lv[0]);
  const float sigma2 = (float)sigma2d;
  const float lam2s2 = (float)(lamd*lamd*sigma2d);

  // F/Q rows, iteration-invariant. [j] = step INTO local elem j (j=0..2).
  v2f aF0[EPT], aF1[EPT], aQ0[EPT], aQ1[EPT];
  {
    const float tm1 = (g0 > 0) ? times[g0-1] : 0.f;
    const float t0 = times[g0];
    const float t1 = times[g0+1];
    const float t2 = times[g0+2];
    compute_fq((g0==0) ? 0.0 : ((double)t0-(double)tm1), lamd, sigma2d, aF0[0],aF1[0],aQ0[0],aQ1[0]);
    compute_fq((double)t1-(double)t0, lamd, sigma2d, aF0[1],aF1[1],aQ0[1],aQ1[1]);
    compute_fq((double)t2-(double)t1, lamd, sigma2d, aF0[2],aF1[2],aQ0[2],aQ1[2]);
  }
  float yf[EPT];
  yf[0] = (float)y[g0]; yf[1] = (float)y[g0+1]; yf[2] = (float)y[g0+2];

  float nat1[EPT], nat2[EPT], qm[EPT], qv[EPT];
  #pragma unroll
  for (int c=0;c<EPT;c++){ nat1[c]=0.f; nat2[c]=1e-6f; qm[c]=0.f; qv[c]=1.f; }

  const bool priorElem = (t == 0);

  for (int it=0; it<4; ++it){
    float (*shFc)[NW] = shF[it & 1];

    // ---- site update (analytic Poisson moment E[e^f]=exp(cm+cv/2)) ----
    #pragma unroll
    for (int c=0;c<EPT;c++){
      const float iqv = frcp(qv[c]);
      const float cp = fmaxf(iqv - nat2[c], 1e-6f);
      const float cv = frcp(cp);
      const float cm = cv*(qm[c]*iqv - nat1[c]);
      const float Ee = __expf(cm + 0.5f*cv);
      const float np  = fmaxf(Ee, 1e-6f);
      const float nn1 = (yf[c] - Ee) + np*cm;
      nat1[c] = 0.5f*nat1[c] + 0.5f*nn1;
      nat2[c] = fmaxf(0.5f*nat2[c] + 0.5f*np, 1e-6f);
    }

    // ---- element tuples (e1,e2 kept for the backward in-thread chain) ----
    const FT part0 = build_felem(priorElem, aF0[0],aF1[0],aQ0[0],aQ1[0],
                                 nat1[0], nat2[0], sigma2, lam2s2);
    const FT e1 = build_felem(false, aF0[1],aF1[1],aQ0[1],aQ1[1],
                              nat1[1], nat2[1], sigma2, lam2s2);
    const FT part1 = comb_f(part0, e1);
    const FT e2 = build_felem(false, aF0[2],aF1[2],aQ0[2],aQ1[2],
                              nat1[2], nat2[2], sigma2, lam2s2);
    const FT part2 = comb_f(part1, e2);

    // ---- interleaved forward prefix scan + backward suffix scan ----
    FT facc = part2;   // will hold composite of lanes 0..l
    FT sacc = part2;   // will hold composite of lanes l..63
    #pragma unroll
    for (int d=1; d<64; d<<=1){
      const FT fpre = shflup(facc, d);
      const FT snxt = shfldn(sacc, d);
      if (lane >= d)     facc = comb_f(fpre, facc);
      if (lane + d < 64) sacc = comb_f(sacc, snxt);
    }
    if (lane == 63) lds_store(shFc, w, facc);
    const FT Sl1 = shfldn(sacc, 1);   // suffix of lanes l+1..63 (lane<63)
    __syncthreads();

    // ---- forward block prefix (BC chain over earlier waves) ----
    BC pre; pre.b=mkv2(0.f,0.f); pre.C0=mkv2(0.f,0.f); pre.C1=mkv2(0.f,0.f);
    for (int j=0; j<w; ++j){
      const FT a = lds_load<FT>(shFc, j);
      pre = comb_bc(pre, a);
    }
    {
      const FT lex = shflup(facc, 1);
      if (lane > 0) pre = comb_bc(pre, lex);
    }
    // forward apply -> filtered moments
    v2f mv[EPT], Pr0[EPT], Pr1[EPT];
    {
      const BC r0 = comb_bc(pre, part0);
      const BC r1 = comb_bc(pre, part1);
      const BC r2 = comb_bc(pre, part2);
      mv[0]=r0.b; Pr0[0]=r0.C0; Pr1[0]=r0.C1;
      mv[1]=r1.b; Pr0[1]=r1.C0; Pr1[1]=r1.C1;
      mv[2]=r2.b; Pr0[2]=r2.C0; Pr1[2]=r2.C1;
    }

    // ---- backward block suffix (eJ chain over later waves) ----
    EJ cr; cr.e=mkv2(0.f,0.f); cr.J0=mkv2(0.f,0.f); cr.J1=mkv2(0.f,0.f);
    for (int j=NW-1; j>w; --j){
      const FT a = lds_load<FT>(shFc, j);
      cr = comb_eJ(a, cr);
    }
    if (lane < 63) cr = comb_eJ(Sl1, cr);
    // per-element suffix info and merge
    const EJ suf2 = cr;
    const EJ suf1 = comb_eJ(e2, suf2);
    const EJ suf0 = comb_eJ(e1, suf1);
    merge_out(mv[0], Pr0[0], Pr1[0], suf0, qm[0], qv[0]);
    merge_out(mv[1], Pr0[1], Pr1[1], suf1, qm[1], qv[1]);
    merge_out(mv[2], Pr0[2], Pr1[2], suf2, qm[2], qv[2]);

    if (it == 3){
      #pragma unroll
      for (int c=0;c<EPT;c++){
        const int g = g0 + c;
        if (g >= cs && g < cs + CHUNK) out[g] = qm[c];
      }
    }
  }
}

// ---------------------------------------------------------------------------
extern "C" void kernel_launch(void* const* d_in, const int* in_sizes, int n_in,
                              void* d_out, int out_size, void* d_ws, size_t ws_size,
                              hipStream_t stream) {
  (void)n_in; (void)out_size; (void)d_ws; (void)ws_size;
  const int N = in_sizes[0];                 // 131072
  const float* times = (const float*)d_in[0];
  const int*   y     = (const int*)d_in[1];
  const float* ll    = (const float*)d_in[2];
  const float* lv    = (const float*)d_in[3];
  float* out = (float*)d_out;

  const int G = N / CHUNK;                   // 256 blocks, one per CU
  fused_kernel<<<G, BLK, 0, stream>>>(times, y, ll, lv, out, N);
}